// Round 1
// baseline (196.005 us; speedup 1.0000x reference)
//
#include <hip/hip_runtime.h>

// DepthScaleCorrector: per (b,c) affine fit of dense depth to sparse depth,
// clipped correction, per-channel masked MSE, argmin channel select.
// Shapes: nsd (16,4,768,1024) f32, sp (16,1,768,1024) f32.
// Outputs (concat f32): corrected 50331648 | best_corrected 12582912 | best_idx 16.

#define HWPIX (768 * 1024)     // 786432 pixels per (b,c)
#define HW4   (HWPIX / 4)      // 196608 float4 per (b,c)
#define VALID_THR 1e-6f
#define MAXD 20.0f

// ws layout (doubles): n[16]@0, y[16]@16, x[64]@32, x2[64]@96, xy[64]@160, err[64]@224
// then floats @byte 2304: scale[64], bias[64]; int bidx[16] @byte 2816.

__device__ inline double wave_sum64(double v) {
#pragma unroll
    for (int o = 32; o > 0; o >>= 1) v += __shfl_down(v, o, 64);
    return v;
}

__global__ __launch_bounds__(256) void k_reduce(const float4* __restrict__ nsd,
                                                const float4* __restrict__ sp,
                                                double* __restrict__ ws) {
    const int b = blockIdx.x >> 8;      // 256 blocks per batch
    const int chunk = blockIdx.x & 255; // each block: 768 float4 per channel
    const int t = threadIdx.x;
    const int sbase = b * HW4 + chunk * 768;

    double lx[4] = {0, 0, 0, 0}, lx2[4] = {0, 0, 0, 0}, lxy[4] = {0, 0, 0, 0};
    double lnv = 0, lyv = 0;
#pragma unroll
    for (int i = 0; i < 3; i++) {
        const int o = i * 256 + t;
        float4 s4 = sp[sbase + o];
        float sv[4] = {s4.x, s4.y, s4.z, s4.w};
        float mv[4];
#pragma unroll
        for (int l = 0; l < 4; l++) {
            mv[l] = (sv[l] > VALID_THR && sv[l] <= MAXD) ? 1.0f : 0.0f;
            lnv += (double)mv[l];
            if (mv[l] != 0.0f) lyv += (double)sv[l];
        }
#pragma unroll
        for (int c = 0; c < 4; c++) {
            float4 x4 = nsd[(b * 4 + c) * HW4 + chunk * 768 + o];
            float xv[4] = {x4.x, x4.y, x4.z, x4.w};
#pragma unroll
            for (int l = 0; l < 4; l++) {
                if (mv[l] != 0.0f) {
                    lx[c]  += (double)xv[l];
                    lx2[c] += (double)(xv[l] * xv[l]);   // f32 product like ref
                    lxy[c] += (double)(xv[l] * sv[l]);
                }
            }
        }
    }

    __shared__ double red[4][14];
    double vals[14] = {lnv, lyv, lx[0], lx[1], lx[2], lx[3],
                       lx2[0], lx2[1], lx2[2], lx2[3],
                       lxy[0], lxy[1], lxy[2], lxy[3]};
    const int wv = t >> 6, lane = t & 63;
#pragma unroll
    for (int j = 0; j < 14; j++) {
        double r = wave_sum64(vals[j]);
        if (lane == 0) red[wv][j] = r;
    }
    __syncthreads();
    if (t < 14) {
        double v = red[0][t] + red[1][t] + red[2][t] + red[3][t];
        if (t == 0)      atomicAdd(&ws[b], v);
        else if (t == 1) atomicAdd(&ws[16 + b], v);
        else if (t < 6)  atomicAdd(&ws[32 + b * 4 + (t - 2)], v);
        else if (t < 10) atomicAdd(&ws[96 + b * 4 + (t - 6)], v);
        else             atomicAdd(&ws[160 + b * 4 + (t - 10)], v);
    }
}

__global__ void k_solve(const double* __restrict__ ws, float* __restrict__ wsf) {
    int i = threadIdx.x;
    if (i >= 64) return;
    int b = i >> 2;
    double n  = ws[b];
    double y  = ws[16 + b];
    double x  = ws[32 + i];
    double x2 = ws[96 + i];
    double xy = ws[160 + i];
    double det = n * x2 - x * x;
    bool ok = (n >= 10.0) && (fabs(det) >= 1e-8);
    double sdet = ok ? det : 1.0;
    double sc = ok ? (n * xy - x * y) / sdet : 1.0;
    double bi = ok ? (x2 * y - x * xy) / sdet : 0.0;
    wsf[i] = (float)sc;
    wsf[64 + i] = (float)bi;
}

__global__ __launch_bounds__(256) void k_apply(const float4* __restrict__ nsd,
                                               const float4* __restrict__ sp,
                                               const float* __restrict__ wsf,
                                               double* __restrict__ ws,
                                               float4* __restrict__ out_corr) {
    const int b = blockIdx.x >> 8;
    const int chunk = blockIdx.x & 255;
    const int t = threadIdx.x;
    float sc[4], bi[4];
#pragma unroll
    for (int c = 0; c < 4; c++) {
        sc[c] = wsf[b * 4 + c];
        bi[c] = wsf[64 + b * 4 + c];
    }
    double lerr[4] = {0, 0, 0, 0};
    const int sbase = b * HW4 + chunk * 768;
#pragma unroll
    for (int i = 0; i < 3; i++) {
        const int o = i * 256 + t;
        float4 s4 = sp[sbase + o];
        float sv[4] = {s4.x, s4.y, s4.z, s4.w};
        float mv[4];
#pragma unroll
        for (int l = 0; l < 4; l++)
            mv[l] = (sv[l] > VALID_THR && sv[l] <= MAXD) ? 1.0f : 0.0f;
#pragma unroll
        for (int c = 0; c < 4; c++) {
            const int off = (b * 4 + c) * HW4 + chunk * 768 + o;
            float4 x4 = nsd[off];
            float4 o4;
            o4.x = fminf(fmaxf(sc[c] * x4.x + bi[c], 0.0f), MAXD);
            o4.y = fminf(fmaxf(sc[c] * x4.y + bi[c], 0.0f), MAXD);
            o4.z = fminf(fmaxf(sc[c] * x4.z + bi[c], 0.0f), MAXD);
            o4.w = fminf(fmaxf(sc[c] * x4.w + bi[c], 0.0f), MAXD);
            out_corr[off] = o4;
            float cv[4] = {o4.x, o4.y, o4.z, o4.w};
#pragma unroll
            for (int l = 0; l < 4; l++) {
                if (mv[l] != 0.0f) {
                    float d = cv[l] - sv[l];
                    lerr[c] += (double)(d * d);
                }
            }
        }
    }

    __shared__ double red[4][4];
    const int wv = t >> 6, lane = t & 63;
#pragma unroll
    for (int j = 0; j < 4; j++) {
        double r = wave_sum64(lerr[j]);
        if (lane == 0) red[wv][j] = r;
    }
    __syncthreads();
    if (t < 4) {
        double v = red[0][t] + red[1][t] + red[2][t] + red[3][t];
        atomicAdd(&ws[224 + b * 4 + t], v);
    }
}

__global__ void k_argmin(const double* __restrict__ ws, int* __restrict__ bidx,
                         float* __restrict__ out_idx) {
    int b = threadIdx.x;
    if (b >= 16) return;
    double n = ws[b];
    double nm = (n > 1.0) ? n : 1.0;
    double best = INFINITY;
    int bi = 0;
    for (int c = 0; c < 4; c++) {
        double e = ws[224 + b * 4 + c];
        double mse = (n > 0.0) ? (e / nm) : INFINITY;
        if (mse < best) { best = mse; bi = c; }
    }
    bidx[b] = bi;
    out_idx[b] = (float)bi;
}

__global__ __launch_bounds__(256) void k_best(const float4* __restrict__ corr,
                                              const int* __restrict__ bidx,
                                              float4* __restrict__ out_best) {
    const int b = blockIdx.x / 768;           // 768 blocks per batch
    const int r = (blockIdx.x % 768) * 256 + threadIdx.x;
    const int c = bidx[b];
    out_best[b * HW4 + r] = corr[(b * 4 + c) * HW4 + r];
}

extern "C" void kernel_launch(void* const* d_in, const int* in_sizes, int n_in,
                              void* d_out, int out_size, void* d_ws, size_t ws_size,
                              hipStream_t stream) {
    const float4* nsd = (const float4*)d_in[0];
    const float4* sp  = (const float4*)d_in[1];
    float* out = (float*)d_out;

    double* ws  = (double*)d_ws;
    float*  wsf = (float*)((char*)d_ws + 2304);
    int*    bidx = (int*)((char*)d_ws + 2816);

    float* out_corr = out;                 // 16*4*768*1024
    float* out_best = out + 50331648;      // 16*1*768*1024
    float* out_idx  = out + 62914560;      // 16

    hipMemsetAsync(d_ws, 0, 3072, stream);
    k_reduce<<<4096, 256, 0, stream>>>(nsd, sp, ws);
    k_solve<<<1, 64, 0, stream>>>(ws, wsf);
    k_apply<<<4096, 256, 0, stream>>>(nsd, sp, wsf, ws, (float4*)out_corr);
    k_argmin<<<1, 64, 0, stream>>>(ws, bidx, out_idx);
    k_best<<<12288, 256, 0, stream>>>((const float4*)out_corr, bidx, (float4*)out_best);
}

// Round 3
// 161.145 us; speedup vs baseline: 1.2163x; 1.2163x over previous
//
#include <hip/hip_runtime.h>

// DepthScaleCorrector: per (b,c) affine fit of dense depth to sparse depth,
// clipped correction, per-channel masked MSE, argmin channel select.
// nsd (16,4,768,1024) f32, sp (16,1,768,1024) f32.
// Outputs (concat f32): corrected 50331648 | best_corrected 12582912 | best_idx 16.
//
// Structure: 5 dispatches, no atomics, no memset.
//   k_reduce  : masked sums (n,y,x,x2,xy) -> per-block f64 partials (scratch in out_best region)
//   k_solve   : reduce partials, solve 2x2 per (b,c) -> scale/bias (ws)
//   k_apply   : corrected = clip(s*x+b), masked err partials -> scratch
//   k_argmin  : reduce err, mse argmin -> bidx + out_idx
//   k_best    : copy best channel (overwrites scratch region)

typedef float f4 __attribute__((ext_vector_type(4)));  // native vec for nontemporal builtins

#define HWPIX (768 * 1024)
#define HW4   (HWPIX / 4)      // 196608 f4 per (b,c)
#define CHUNKS 128             // blocks per batch in the big kernels
#define F4PC  (HW4 / CHUNKS)   // 1536 f4 per chunk per channel
#define ITERS (F4PC / 256)     // 6
#define VALID_THR 1e-6f
#define MAXD 20.0f
#define NPART 2048             // total blocks in big kernels (16*128)

__device__ inline double wave_sum64(double v) {
#pragma unroll
    for (int o = 32; o > 0; o >>= 1) v += __shfl_down(v, o, 64);
    return v;
}

// ---------------- pass 1: masked reductions ----------------
__global__ __launch_bounds__(256) void k_reduce(const f4* __restrict__ nsd,
                                                const f4* __restrict__ sp,
                                                double* __restrict__ part) {
    const int blk = blockIdx.x;
    const int b = blk >> 7;
    const int chunk = blk & (CHUNKS - 1);
    const int t = threadIdx.x;
    const int sbase = b * HW4 + chunk * F4PC;

    float lnv = 0.f, lyv = 0.f;
    float lx[4] = {0, 0, 0, 0}, lx2[4] = {0, 0, 0, 0}, lxy[4] = {0, 0, 0, 0};
#pragma unroll
    for (int i = 0; i < ITERS; i++) {
        const int o = i * 256 + t;
        f4 s4 = sp[sbase + o];
        float mv[4], svm[4];
#pragma unroll
        for (int l = 0; l < 4; l++) {
            float sv = s4[l];
            mv[l] = (sv > VALID_THR && sv <= MAXD) ? 1.0f : 0.0f;
            svm[l] = sv * mv[l];
            lnv += mv[l];
            lyv += svm[l];
        }
#pragma unroll
        for (int c = 0; c < 4; c++) {
            f4 x4 = nsd[(b * 4 + c) * HW4 + chunk * F4PC + o];
#pragma unroll
            for (int l = 0; l < 4; l++) {
                float xv = x4[l];
                lx[c]  = fmaf(xv, mv[l], lx[c]);
                lx2[c] = fmaf(xv * xv, mv[l], lx2[c]);
                lxy[c] = fmaf(xv, svm[l], lxy[c]);
            }
        }
    }

    double vals[14] = {(double)lnv, (double)lyv,
                       (double)lx[0],  (double)lx[1],  (double)lx[2],  (double)lx[3],
                       (double)lx2[0], (double)lx2[1], (double)lx2[2], (double)lx2[3],
                       (double)lxy[0], (double)lxy[1], (double)lxy[2], (double)lxy[3]};
    __shared__ double red[4][14];
    const int wv = t >> 6, lane = t & 63;
#pragma unroll
    for (int j = 0; j < 14; j++) {
        double r = wave_sum64(vals[j]);
        if (lane == 0) red[wv][j] = r;
    }
    __syncthreads();
    if (t < 14) {
        part[t * NPART + blk] = red[0][t] + red[1][t] + red[2][t] + red[3][t];
    }
}

// ---------------- solve 2x2 per (b,c) ----------------
__global__ void k_solve(const double* __restrict__ part, float* __restrict__ wsf,
                        double* __restrict__ wsn) {
    const int t = threadIdx.x;          // 896 threads = 14 waves
    const int j = t >> 6, lane = t & 63;
    const int b = lane >> 2, p = lane & 3;
    __shared__ double sred[14][16];

    double s = 0.0;
#pragma unroll
    for (int k = 0; k < 32; k++)
        s += part[j * NPART + b * CHUNKS + p * 32 + k];
    s += __shfl_down(s, 2, 64);
    s += __shfl_down(s, 1, 64);
    if (p == 0) sred[j][b] = s;
    __syncthreads();

    if (t < 64) {
        const int bb = t >> 2, c = t & 3;
        double n  = sred[0][bb];
        double y  = sred[1][bb];
        double x  = sred[2 + c][bb];
        double x2 = sred[6 + c][bb];
        double xy = sred[10 + c][bb];
        double det = n * x2 - x * x;
        bool ok = (n >= 10.0) && (fabs(det) >= 1e-8);
        double sdet = ok ? det : 1.0;
        wsf[t]      = (float)(ok ? (n * xy - x * y) / sdet : 1.0);
        wsf[64 + t] = (float)(ok ? (x2 * y - x * xy) / sdet : 0.0);
        if (c == 0) wsn[bb] = n;
    }
}

// ---------------- pass 2: apply + err reduction ----------------
__global__ __launch_bounds__(256) void k_apply(const f4* __restrict__ nsd,
                                               const f4* __restrict__ sp,
                                               const float* __restrict__ wsf,
                                               double* __restrict__ epart,
                                               f4* __restrict__ out_corr) {
    const int blk = blockIdx.x;
    const int b = blk >> 7;
    const int chunk = blk & (CHUNKS - 1);
    const int t = threadIdx.x;
    float sc[4], bi[4];
#pragma unroll
    for (int c = 0; c < 4; c++) {
        sc[c] = wsf[b * 4 + c];
        bi[c] = wsf[64 + b * 4 + c];
    }
    float lerr[4] = {0, 0, 0, 0};
    const int sbase = b * HW4 + chunk * F4PC;
#pragma unroll
    for (int i = 0; i < ITERS; i++) {
        const int o = i * 256 + t;
        f4 s4 = __builtin_nontemporal_load(&sp[sbase + o]);
        float mv[4];
#pragma unroll
        for (int l = 0; l < 4; l++)
            mv[l] = (s4[l] > VALID_THR && s4[l] <= MAXD) ? 1.0f : 0.0f;
#pragma unroll
        for (int c = 0; c < 4; c++) {
            const int off = (b * 4 + c) * HW4 + chunk * F4PC + o;
            f4 x4 = __builtin_nontemporal_load(&nsd[off]);
            f4 o4;
#pragma unroll
            for (int l = 0; l < 4; l++)
                o4[l] = fminf(fmaxf(fmaf(sc[c], x4[l], bi[c]), 0.0f), MAXD);
            out_corr[off] = o4;
#pragma unroll
            for (int l = 0; l < 4; l++) {
                float d = o4[l] - s4[l];
                lerr[c] = fmaf(d * d, mv[l], lerr[c]);
            }
        }
    }

    __shared__ double red[4][4];
    const int wv = t >> 6, lane = t & 63;
#pragma unroll
    for (int j = 0; j < 4; j++) {
        double r = wave_sum64((double)lerr[j]);
        if (lane == 0) red[wv][j] = r;
    }
    __syncthreads();
    if (t < 4) {
        epart[blk * 4 + t] = red[0][t] + red[1][t] + red[2][t] + red[3][t];
    }
}

// ---------------- mse argmin ----------------
__global__ void k_argmin(const double* __restrict__ epart, const double* __restrict__ wsn,
                         int* __restrict__ bidx, float* __restrict__ out_idx) {
    const int t = threadIdx.x;          // 64 threads
    const int b = t >> 2, c = t & 3;
    __shared__ double esum[64];
    double s = 0.0;
    for (int chunk = 0; chunk < CHUNKS; chunk++)
        s += epart[(b * CHUNKS + chunk) * 4 + c];
    esum[t] = s;
    __syncthreads();
    if (t < 16) {
        double n = wsn[t];
        double nm = (n > 1.0) ? n : 1.0;
        double best = INFINITY;
        int bc = 0;
        for (int cc = 0; cc < 4; cc++) {
            double mse = (n > 0.0) ? (esum[t * 4 + cc] / nm) : INFINITY;
            if (mse < best) { best = mse; bc = cc; }
        }
        bidx[t] = bc;
        out_idx[t] = (float)bc;
    }
}

// ---------------- best-channel copy ----------------
__global__ __launch_bounds__(256) void k_best(const f4* __restrict__ corr,
                                              const int* __restrict__ bidx,
                                              f4* __restrict__ out_best) {
    const int b = blockIdx.x / 192;     // 192 blocks per batch
    const int i = blockIdx.x % 192;
    const int c = bidx[b];
    const int base = (b * 4 + c) * HW4 + i * 1024 + threadIdx.x;
    const int obase = b * HW4 + i * 1024 + threadIdx.x;
#pragma unroll
    for (int k = 0; k < 4; k++) {
        f4 v = __builtin_nontemporal_load(&corr[base + k * 256]);
        __builtin_nontemporal_store(v, &out_best[obase + k * 256]);
    }
}

extern "C" void kernel_launch(void* const* d_in, const int* in_sizes, int n_in,
                              void* d_out, int out_size, void* d_ws, size_t ws_size,
                              hipStream_t stream) {
    const f4* nsd = (const f4*)d_in[0];
    const f4* sp  = (const f4*)d_in[1];
    float* out = (float*)d_out;

    float* out_corr = out;                 // 16*4*768*1024
    float* out_best = out + 50331648;      // 16*1*768*1024 (used as scratch until k_best)
    float* out_idx  = out + 62914560;      // 16

    // scratch carved from the out_best region (fully overwritten by k_best)
    double* part  = (double*)out_best;              // 14*2048 doubles = 224 KB
    double* epart = (double*)out_best + 14 * NPART; // 2048*4 doubles  = 64 KB

    // tiny cross-kernel state in d_ws
    float*  wsf  = (float*)d_ws;                    // scale[64], bias[64]
    double* wsn  = (double*)((char*)d_ws + 512);    // n[16]
    int*    bidx = (int*)((char*)d_ws + 640);       // best idx[16]

    k_reduce<<<NPART, 256, 0, stream>>>(nsd, sp, part);
    k_solve<<<1, 896, 0, stream>>>(part, wsf, wsn);
    k_apply<<<NPART, 256, 0, stream>>>(nsd, sp, wsf, epart, (f4*)out_corr);
    k_argmin<<<1, 64, 0, stream>>>(epart, wsn, bidx, out_idx);
    k_best<<<3072, 256, 0, stream>>>((const f4*)out_corr, bidx, (f4*)out_best);
}

// Round 4
// 148.660 us; speedup vs baseline: 1.3185x; 1.0840x over previous
//
#include <hip/hip_runtime.h>

// DepthScaleCorrector: per (b,c) affine fit of dense depth to sparse depth,
// clipped correction, per-channel masked MSE, argmin channel select.
// nsd (16,4,768,1024) f32, sp (16,1,768,1024) f32.
// Outputs (concat f32): corrected 50331648 | best_corrected 12582912 | best_idx 16.
//
// Structure: 5 dispatches, no atomics, no memset.
//   k_reduce  : masked sums (n,y,x,x2,xy) -> per-block f64 partials (scratch in out_best region)
//               regular loads: allocate inputs into L3 (251 MB < 256 MB L3)
//   k_solve   : reduce partials, solve 2x2 per (b,c) -> scale/bias (ws)
//   k_apply   : corrected = clip(s*x+b) [NT store: don't evict L3-resident inputs],
//               NT loads (last use), masked err partials -> scratch
//   k_argmin  : reduce err, mse argmin -> bidx + out_idx
//   k_best    : copy best channel (reads corrected from HBM, NT both ways)

typedef float f4 __attribute__((ext_vector_type(4)));  // native vec for nontemporal builtins

#define HWPIX (768 * 1024)
#define HW4   (HWPIX / 4)      // 196608 f4 per (b,c)
#define CHUNKS 128             // blocks per batch in the big kernels
#define F4PC  (HW4 / CHUNKS)   // 1536 f4 per chunk per channel
#define ITERS (F4PC / 256)     // 6
#define VALID_THR 1e-6f
#define MAXD 20.0f
#define NPART 2048             // total blocks in big kernels (16*128)

__device__ inline double wave_sum64(double v) {
#pragma unroll
    for (int o = 32; o > 0; o >>= 1) v += __shfl_down(v, o, 64);
    return v;
}

// ---------------- pass 1: masked reductions ----------------
__global__ __launch_bounds__(256) void k_reduce(const f4* __restrict__ nsd,
                                                const f4* __restrict__ sp,
                                                double* __restrict__ part) {
    const int blk = blockIdx.x;
    const int b = blk >> 7;
    const int chunk = blk & (CHUNKS - 1);
    const int t = threadIdx.x;
    const int sbase = b * HW4 + chunk * F4PC;

    float lnv = 0.f, lyv = 0.f;
    float lx[4] = {0, 0, 0, 0}, lx2[4] = {0, 0, 0, 0}, lxy[4] = {0, 0, 0, 0};
#pragma unroll
    for (int i = 0; i < ITERS; i++) {
        const int o = i * 256 + t;
        f4 s4 = sp[sbase + o];
        float mv[4], svm[4];
#pragma unroll
        for (int l = 0; l < 4; l++) {
            float sv = s4[l];
            mv[l] = (sv > VALID_THR && sv <= MAXD) ? 1.0f : 0.0f;
            svm[l] = sv * mv[l];
            lnv += mv[l];
            lyv += svm[l];
        }
#pragma unroll
        for (int c = 0; c < 4; c++) {
            f4 x4 = nsd[(b * 4 + c) * HW4 + chunk * F4PC + o];
#pragma unroll
            for (int l = 0; l < 4; l++) {
                float xv = x4[l];
                lx[c]  = fmaf(xv, mv[l], lx[c]);
                lx2[c] = fmaf(xv * xv, mv[l], lx2[c]);
                lxy[c] = fmaf(xv, svm[l], lxy[c]);
            }
        }
    }

    double vals[14] = {(double)lnv, (double)lyv,
                       (double)lx[0],  (double)lx[1],  (double)lx[2],  (double)lx[3],
                       (double)lx2[0], (double)lx2[1], (double)lx2[2], (double)lx2[3],
                       (double)lxy[0], (double)lxy[1], (double)lxy[2], (double)lxy[3]};
    __shared__ double red[4][14];
    const int wv = t >> 6, lane = t & 63;
#pragma unroll
    for (int j = 0; j < 14; j++) {
        double r = wave_sum64(vals[j]);
        if (lane == 0) red[wv][j] = r;
    }
    __syncthreads();
    if (t < 14) {
        part[t * NPART + blk] = red[0][t] + red[1][t] + red[2][t] + red[3][t];
    }
}

// ---------------- solve 2x2 per (b,c) ----------------
__global__ void k_solve(const double* __restrict__ part, float* __restrict__ wsf,
                        double* __restrict__ wsn) {
    const int t = threadIdx.x;          // 896 threads = 14 waves
    const int j = t >> 6, lane = t & 63;
    const int b = lane >> 2, p = lane & 3;
    __shared__ double sred[14][16];

    double s = 0.0;
#pragma unroll
    for (int k = 0; k < 32; k++)
        s += part[j * NPART + b * CHUNKS + p * 32 + k];
    s += __shfl_down(s, 2, 64);
    s += __shfl_down(s, 1, 64);
    if (p == 0) sred[j][b] = s;
    __syncthreads();

    if (t < 64) {
        const int bb = t >> 2, c = t & 3;
        double n  = sred[0][bb];
        double y  = sred[1][bb];
        double x  = sred[2 + c][bb];
        double x2 = sred[6 + c][bb];
        double xy = sred[10 + c][bb];
        double det = n * x2 - x * x;
        bool ok = (n >= 10.0) && (fabs(det) >= 1e-8);
        double sdet = ok ? det : 1.0;
        wsf[t]      = (float)(ok ? (n * xy - x * y) / sdet : 1.0);
        wsf[64 + t] = (float)(ok ? (x2 * y - x * xy) / sdet : 0.0);
        if (c == 0) wsn[bb] = n;
    }
}

// ---------------- pass 2: apply + err reduction ----------------
__global__ __launch_bounds__(256) void k_apply(const f4* __restrict__ nsd,
                                               const f4* __restrict__ sp,
                                               const float* __restrict__ wsf,
                                               double* __restrict__ epart,
                                               f4* __restrict__ out_corr) {
    const int blk = blockIdx.x;
    const int b = blk >> 7;
    const int chunk = blk & (CHUNKS - 1);
    const int t = threadIdx.x;
    float sc[4], bi[4];
#pragma unroll
    for (int c = 0; c < 4; c++) {
        sc[c] = wsf[b * 4 + c];
        bi[c] = wsf[64 + b * 4 + c];
    }
    float lerr[4] = {0, 0, 0, 0};
    const int sbase = b * HW4 + chunk * F4PC;
#pragma unroll
    for (int i = 0; i < ITERS; i++) {
        const int o = i * 256 + t;
        f4 s4 = __builtin_nontemporal_load(&sp[sbase + o]);
        float mv[4];
#pragma unroll
        for (int l = 0; l < 4; l++)
            mv[l] = (s4[l] > VALID_THR && s4[l] <= MAXD) ? 1.0f : 0.0f;
#pragma unroll
        for (int c = 0; c < 4; c++) {
            const int off = (b * 4 + c) * HW4 + chunk * F4PC + o;
            f4 x4 = __builtin_nontemporal_load(&nsd[off]);
            f4 o4;
#pragma unroll
            for (int l = 0; l < 4; l++)
                o4[l] = fminf(fmaxf(fmaf(sc[c], x4[l], bi[c]), 0.0f), MAXD);
            __builtin_nontemporal_store(o4, &out_corr[off]);
#pragma unroll
            for (int l = 0; l < 4; l++) {
                float d = o4[l] - s4[l];
                lerr[c] = fmaf(d * d, mv[l], lerr[c]);
            }
        }
    }

    __shared__ double red[4][4];
    const int wv = t >> 6, lane = t & 63;
#pragma unroll
    for (int j = 0; j < 4; j++) {
        double r = wave_sum64((double)lerr[j]);
        if (lane == 0) red[wv][j] = r;
    }
    __syncthreads();
    if (t < 4) {
        epart[blk * 4 + t] = red[0][t] + red[1][t] + red[2][t] + red[3][t];
    }
}

// ---------------- mse argmin ----------------
__global__ void k_argmin(const double* __restrict__ epart, const double* __restrict__ wsn,
                         int* __restrict__ bidx, float* __restrict__ out_idx) {
    const int t = threadIdx.x;          // 64 threads
    const int b = t >> 2, c = t & 3;
    __shared__ double esum[64];
    double s = 0.0;
    for (int chunk = 0; chunk < CHUNKS; chunk++)
        s += epart[(b * CHUNKS + chunk) * 4 + c];
    esum[t] = s;
    __syncthreads();
    if (t < 16) {
        double n = wsn[t];
        double nm = (n > 1.0) ? n : 1.0;
        double best = INFINITY;
        int bc = 0;
        for (int cc = 0; cc < 4; cc++) {
            double mse = (n > 0.0) ? (esum[t * 4 + cc] / nm) : INFINITY;
            if (mse < best) { best = mse; bc = cc; }
        }
        bidx[t] = bc;
        out_idx[t] = (float)bc;
    }
}

// ---------------- best-channel copy ----------------
__global__ __launch_bounds__(256) void k_best(const f4* __restrict__ corr,
                                              const int* __restrict__ bidx,
                                              f4* __restrict__ out_best) {
    const int b = blockIdx.x / 192;     // 192 blocks per batch
    const int i = blockIdx.x % 192;
    const int c = bidx[b];
    const int base = (b * 4 + c) * HW4 + i * 1024 + threadIdx.x;
    const int obase = b * HW4 + i * 1024 + threadIdx.x;
#pragma unroll
    for (int k = 0; k < 4; k++) {
        f4 v = __builtin_nontemporal_load(&corr[base + k * 256]);
        __builtin_nontemporal_store(v, &out_best[obase + k * 256]);
    }
}

extern "C" void kernel_launch(void* const* d_in, const int* in_sizes, int n_in,
                              void* d_out, int out_size, void* d_ws, size_t ws_size,
                              hipStream_t stream) {
    const f4* nsd = (const f4*)d_in[0];
    const f4* sp  = (const f4*)d_in[1];
    float* out = (float*)d_out;

    float* out_corr = out;                 // 16*4*768*1024
    float* out_best = out + 50331648;      // 16*1*768*1024 (used as scratch until k_best)
    float* out_idx  = out + 62914560;      // 16

    // scratch carved from the out_best region (fully overwritten by k_best)
    double* part  = (double*)out_best;              // 14*2048 doubles = 224 KB
    double* epart = (double*)out_best + 14 * NPART; // 2048*4 doubles  = 64 KB

    // tiny cross-kernel state in d_ws
    float*  wsf  = (float*)d_ws;                    // scale[64], bias[64]
    double* wsn  = (double*)((char*)d_ws + 512);    // n[16]
    int*    bidx = (int*)((char*)d_ws + 640);       // best idx[16]

    k_reduce<<<NPART, 256, 0, stream>>>(nsd, sp, part);
    k_solve<<<1, 896, 0, stream>>>(part, wsf, wsn);
    k_apply<<<NPART, 256, 0, stream>>>(nsd, sp, wsf, epart, (f4*)out_corr);
    k_argmin<<<1, 64, 0, stream>>>(epart, wsn, bidx, out_idx);
    k_best<<<3072, 256, 0, stream>>>((const f4*)out_corr, bidx, (f4*)out_best);
}

// Round 5
// 141.773 us; speedup vs baseline: 1.3825x; 1.0486x over previous
//
#include <hip/hip_runtime.h>

// DepthScaleCorrector: per (b,c) affine fit, clipped correction, masked MSE argmin.
// nsd (16,4,768,1024) f32, sp (16,1,768,1024) f32.
// Outputs (concat f32): corrected 50331648 | best_corrected 12582912 | best_idx 16.
//
// Analytic-MSE structure (4 dispatches):
//   k_reduce : 23 masked stats per block (n, Σsm, Σs²m; per-c Σxm, Σx²m, Σxsm, min/max of masked x)
//   k_solve  : reduce partials, solve 2x2, ANALYTIC mse (valid iff no masked pixel clips —
//              provable from masked min/max), argmin -> bidx + flags; zeroes esum
//   k_apply  : corrected = clip(a*x+b) [NT], fast: also writes out_best inline (no sp read!);
//              slow (clip detected): exact per-pixel err -> f64 atomics into esum
//   k_best   : fast batches early-exit; slow batches argmin from esum + copy

typedef float f4 __attribute__((ext_vector_type(4)));

#define HWPIX (768 * 1024)
#define HW4   (HWPIX / 4)      // 196608 f4 per (b,c)
#define CHUNKS 128             // blocks per batch in the big kernels
#define F4PC  (HW4 / CHUNKS)   // 1536 f4 per chunk per channel
#define ITERS (F4PC / 256)     // 6
#define VALID_THR 1e-6f
#define MAXD 20.0f
#define NPART 2048             // 16*128
#define NSTAT 23               // 0:n 1:y 2:y2 3+c:x 7+c:x2 11+c:xy 15+c:xmin 19+c:xmax

__device__ inline double wred_sum(double v) {
#pragma unroll
    for (int o = 32; o > 0; o >>= 1) v += __shfl_down(v, o, 64);
    return v;
}
__device__ inline double wred_min(double v) {
#pragma unroll
    for (int o = 32; o > 0; o >>= 1) v = fmin(v, __shfl_down(v, o, 64));
    return v;
}
__device__ inline double wred_max(double v) {
#pragma unroll
    for (int o = 32; o > 0; o >>= 1) v = fmax(v, __shfl_down(v, o, 64));
    return v;
}

// ---------------- pass 1: masked stats ----------------
__global__ __launch_bounds__(256) void k_reduce(const f4* __restrict__ nsd,
                                                const f4* __restrict__ sp,
                                                double* __restrict__ part) {
    const int blk = blockIdx.x;
    const int b = blk >> 7;
    const int chunk = blk & (CHUNKS - 1);
    const int t = threadIdx.x;
    const int sbase = b * HW4 + chunk * F4PC;

    float lnv = 0.f, lyv = 0.f, ly2 = 0.f;
    float lx[4] = {0, 0, 0, 0}, lx2[4] = {0, 0, 0, 0}, lxy[4] = {0, 0, 0, 0};
    float lmn[4] = {INFINITY, INFINITY, INFINITY, INFINITY};
    float lmx[4] = {-INFINITY, -INFINITY, -INFINITY, -INFINITY};
#pragma unroll
    for (int i = 0; i < ITERS; i++) {
        const int o = i * 256 + t;
        f4 s4 = sp[sbase + o];
        float mv[4], svm[4];
#pragma unroll
        for (int l = 0; l < 4; l++) {
            float sv = s4[l];
            mv[l] = (sv > VALID_THR && sv <= MAXD) ? 1.0f : 0.0f;
            svm[l] = sv * mv[l];
            lnv += mv[l];
            lyv += svm[l];
            ly2 = fmaf(sv * sv, mv[l], ly2);
        }
#pragma unroll
        for (int c = 0; c < 4; c++) {
            f4 x4 = nsd[(b * 4 + c) * HW4 + chunk * F4PC + o];
#pragma unroll
            for (int l = 0; l < 4; l++) {
                float xv = x4[l];
                lx[c]  = fmaf(xv, mv[l], lx[c]);
                lx2[c] = fmaf(xv * xv, mv[l], lx2[c]);
                lxy[c] = fmaf(xv, svm[l], lxy[c]);
                lmn[c] = fminf(lmn[c], mv[l] != 0.f ? xv : INFINITY);
                lmx[c] = fmaxf(lmx[c], mv[l] != 0.f ? xv : -INFINITY);
            }
        }
    }

    double vals[NSTAT] = {(double)lnv, (double)lyv, (double)ly2,
                          (double)lx[0],  (double)lx[1],  (double)lx[2],  (double)lx[3],
                          (double)lx2[0], (double)lx2[1], (double)lx2[2], (double)lx2[3],
                          (double)lxy[0], (double)lxy[1], (double)lxy[2], (double)lxy[3],
                          (double)lmn[0], (double)lmn[1], (double)lmn[2], (double)lmn[3],
                          (double)lmx[0], (double)lmx[1], (double)lmx[2], (double)lmx[3]};
    __shared__ double red[4][NSTAT];
    const int wv = t >> 6, lane = t & 63;
#pragma unroll
    for (int j = 0; j < NSTAT; j++) {
        double r = (j < 15) ? wred_sum(vals[j])
                 : (j < 19) ? wred_min(vals[j])
                            : wred_max(vals[j]);
        if (lane == 0) red[wv][j] = r;
    }
    __syncthreads();
    if (t < NSTAT) {
        double a0 = red[0][t], a1 = red[1][t], a2 = red[2][t], a3 = red[3][t];
        double r = (t < 15) ? (a0 + a1 + a2 + a3)
                 : (t < 19) ? fmin(fmin(a0, a1), fmin(a2, a3))
                            : fmax(fmax(a0, a1), fmax(a2, a3));
        part[t * NPART + blk] = r;
    }
}

// ---------------- solve + analytic mse + argmin ----------------
__global__ void k_solve(const double* __restrict__ part, float* __restrict__ wsf,
                        double* __restrict__ wsn, int* __restrict__ bidx,
                        int* __restrict__ flags, double* __restrict__ esum,
                        float* __restrict__ out_idx) {
    const int t = threadIdx.x;          // 384 threads
    __shared__ double sred[NSTAT][16];
    __shared__ double smse[64];
    __shared__ int snoclip[64];

    if (t < NSTAT * 16) {
        const int j = t >> 4, b = t & 15;
        double acc = (j < 15) ? 0.0 : (j < 19 ? INFINITY : -INFINITY);
        for (int k = 0; k < CHUNKS; k++) {
            double v = part[j * NPART + b * CHUNKS + k];
            acc = (j < 15) ? (acc + v) : (j < 19 ? fmin(acc, v) : fmax(acc, v));
        }
        sred[j][b] = acc;
    }
    __syncthreads();

    if (t < 64) {
        const int b = t >> 2, c = t & 3;
        double n   = sred[0][b];
        double y   = sred[1][b];
        double y2  = sred[2][b];
        double x   = sred[3 + c][b];
        double x2  = sred[7 + c][b];
        double xy  = sred[11 + c][b];
        double xmn = sred[15 + c][b];
        double xmx = sred[19 + c][b];
        double det = n * x2 - x * x;
        bool ok = (n >= 10.0) && (fabs(det) >= 1e-8);
        double sdet = ok ? det : 1.0;
        double ad = ok ? (n * xy - x * y) / sdet : 1.0;
        double bd = ok ? (x2 * y - x * xy) / sdet : 0.0;
        float af = (float)ad, bf = (float)bd;
        wsf[t] = af;
        wsf[64 + t] = bf;
        if (c == 0) wsn[b] = n;
        esum[t] = 0.0;

        double mse;
        int noclip;
        if (n <= 0.0) {
            mse = INFINITY;
            noclip = 1;
        } else {
            double A = (double)af, B = (double)bf;
            double e0 = A * xmn + B, e1 = A * xmx + B;
            double clo = fmin(e0, e1), chi = fmax(e0, e1);
            noclip = (clo >= 0.0 && chi <= (double)MAXD) ? 1 : 0;
            mse = (A * A * x2 + 2.0 * A * B * x + B * B * n
                   - 2.0 * A * xy - 2.0 * B * y + y2) / fmax(n, 1.0);
        }
        smse[t] = mse;
        snoclip[t] = noclip;
    }
    __syncthreads();

    if (t < 16) {
        int fast = snoclip[t * 4] & snoclip[t * 4 + 1] & snoclip[t * 4 + 2] & snoclip[t * 4 + 3];
        flags[t] = fast ? 0 : 1;
        if (fast) {
            double best = INFINITY;
            int bc = 0;
            for (int cc = 0; cc < 4; cc++) {
                double m = smse[t * 4 + cc];
                if (m < best) { best = m; bc = cc; }
            }
            bidx[t] = bc;
            out_idx[t] = (float)bc;
        }
    }
}

// ---------------- pass 2: apply (+ exact err only if clipping detected) ----------------
__global__ __launch_bounds__(256) void k_apply(const f4* __restrict__ nsd,
                                               const f4* __restrict__ sp,
                                               const float* __restrict__ wsf,
                                               const int* __restrict__ bidx,
                                               const int* __restrict__ flags,
                                               double* __restrict__ esum,
                                               f4* __restrict__ out_corr,
                                               f4* __restrict__ out_best) {
    const int blk = blockIdx.x;
    const int b = blk >> 7;
    const int chunk = blk & (CHUNKS - 1);
    const int t = threadIdx.x;
    float sc[4], bi[4];
#pragma unroll
    for (int c = 0; c < 4; c++) {
        sc[c] = wsf[b * 4 + c];
        bi[c] = wsf[64 + b * 4 + c];
    }
    const int sbase = b * HW4 + chunk * F4PC;

    if (flags[b] == 0) {
        // fast path: no sp read, no err reduction; inline best-channel write
        const int cbest = bidx[b];
#pragma unroll
        for (int i = 0; i < ITERS; i++) {
            const int o = i * 256 + t;
#pragma unroll
            for (int c = 0; c < 4; c++) {
                const int off = (b * 4 + c) * HW4 + chunk * F4PC + o;
                f4 x4 = __builtin_nontemporal_load(&nsd[off]);
                f4 o4;
#pragma unroll
                for (int l = 0; l < 4; l++)
                    o4[l] = fminf(fmaxf(fmaf(sc[c], x4[l], bi[c]), 0.0f), MAXD);
                __builtin_nontemporal_store(o4, &out_corr[off]);
                if (c == cbest)
                    __builtin_nontemporal_store(o4, &out_best[sbase + o]);
            }
        }
        return;
    }

    // slow path (a masked pixel would clip): exact per-pixel err
    float lerr[4] = {0, 0, 0, 0};
#pragma unroll
    for (int i = 0; i < ITERS; i++) {
        const int o = i * 256 + t;
        f4 s4 = __builtin_nontemporal_load(&sp[sbase + o]);
        float mv[4];
#pragma unroll
        for (int l = 0; l < 4; l++)
            mv[l] = (s4[l] > VALID_THR && s4[l] <= MAXD) ? 1.0f : 0.0f;
#pragma unroll
        for (int c = 0; c < 4; c++) {
            const int off = (b * 4 + c) * HW4 + chunk * F4PC + o;
            f4 x4 = __builtin_nontemporal_load(&nsd[off]);
            f4 o4;
#pragma unroll
            for (int l = 0; l < 4; l++)
                o4[l] = fminf(fmaxf(fmaf(sc[c], x4[l], bi[c]), 0.0f), MAXD);
            __builtin_nontemporal_store(o4, &out_corr[off]);
#pragma unroll
            for (int l = 0; l < 4; l++) {
                float d = o4[l] - s4[l];
                lerr[c] = fmaf(d * d, mv[l], lerr[c]);
            }
        }
    }
    __shared__ double red[4][4];
    const int wv = t >> 6, lane = t & 63;
#pragma unroll
    for (int j = 0; j < 4; j++) {
        double r = wred_sum((double)lerr[j]);
        if (lane == 0) red[wv][j] = r;
    }
    __syncthreads();
    if (t < 4)
        atomicAdd(&esum[b * 4 + t], red[0][t] + red[1][t] + red[2][t] + red[3][t]);
}

// ---------------- slow-path best copy ----------------
__global__ __launch_bounds__(256) void k_best(const f4* __restrict__ corr,
                                              const int* __restrict__ flags,
                                              const double* __restrict__ esum,
                                              const double* __restrict__ wsn,
                                              f4* __restrict__ out_best,
                                              float* __restrict__ out_idx) {
    const int b = blockIdx.x / 192;
    if (flags[b] == 0) return;          // out_best already written by k_apply
    const int i = blockIdx.x % 192;
    double n = wsn[b];
    double nm = fmax(n, 1.0);
    double best = INFINITY;
    int bc = 0;
    for (int cc = 0; cc < 4; cc++) {
        double mse = (n > 0.0) ? (esum[b * 4 + cc] / nm) : INFINITY;
        if (mse < best) { best = mse; bc = cc; }
    }
    if (i == 0 && threadIdx.x == 0) out_idx[b] = (float)bc;
    const int base = (b * 4 + bc) * HW4 + i * 1024 + threadIdx.x;
    const int obase = b * HW4 + i * 1024 + threadIdx.x;
#pragma unroll
    for (int k = 0; k < 4; k++) {
        f4 v = __builtin_nontemporal_load(&corr[base + k * 256]);
        __builtin_nontemporal_store(v, &out_best[obase + k * 256]);
    }
}

extern "C" void kernel_launch(void* const* d_in, const int* in_sizes, int n_in,
                              void* d_out, int out_size, void* d_ws, size_t ws_size,
                              hipStream_t stream) {
    const f4* nsd = (const f4*)d_in[0];
    const f4* sp  = (const f4*)d_in[1];
    float* out = (float*)d_out;

    float* out_corr = out;                 // 16*4*768*1024
    float* out_best = out + 50331648;      // 16*1*768*1024
    float* out_idx  = out + 62914560;      // 16

    // pass-1 partials live in the out_best region (consumed by k_solve before
    // k_apply/k_best write real data there)
    double* part = (double*)out_best;      // 23*2048 doubles = 368 KB

    // tiny cross-kernel state in d_ws (~1.3 KB)
    float*  wsf   = (float*)d_ws;                    // scale[64], bias[64]
    double* wsn   = (double*)((char*)d_ws + 512);    // n[16]
    int*    bidx  = (int*)((char*)d_ws + 640);       // best idx[16]
    int*    flags = (int*)((char*)d_ws + 704);       // slow-path flags[16]
    double* esum  = (double*)((char*)d_ws + 768);    // exact err sums[64]

    k_reduce<<<NPART, 256, 0, stream>>>(nsd, sp, part);
    k_solve<<<1, 384, 0, stream>>>(part, wsf, wsn, bidx, flags, esum, out_idx);
    k_apply<<<NPART, 256, 0, stream>>>(nsd, sp, wsf, bidx, flags, esum,
                                       (f4*)out_corr, (f4*)out_best);
    k_best<<<3072, 256, 0, stream>>>((const f4*)out_corr, flags, esum, wsn,
                                     (f4*)out_best, out_idx);
}

// Round 6
// 129.148 us; speedup vs baseline: 1.5177x; 1.0978x over previous
//
#include <hip/hip_runtime.h>

// DepthScaleCorrector: per (b,c) affine fit, clipped correction, masked MSE argmin.
// nsd (16,4,768,1024) f32, sp (16,1,768,1024) f32.
// Outputs (concat f32): corrected 50331648 | best_corrected 12582912 | best_idx 16.
//
// Analytic-MSE structure (4 dispatches):
//   k_reduce : 23 masked stats per block (regular loads -> allocate inputs in L3; 251MB < 256MB)
//   k_solve  : reduce partials (pair-split, 736 thr), solve 2x2, analytic MSE + clip-proof,
//              argmin -> bidx/flags (fast path decided BEFORE pass 2)
//   k_apply  : corrected = clip(a*x+b); REGULAR loads (L3 hits, keep inputs MRU),
//              NT stores (don't evict inputs); fast path writes out_best inline, no sp read
//   k_best   : fast batches early-exit; slow-path fallback (exact err argmin + copy)

typedef float f4 __attribute__((ext_vector_type(4)));

#define HWPIX (768 * 1024)
#define HW4   (HWPIX / 4)      // 196608 f4 per (b,c)
#define CHUNKS 128             // blocks per batch in the big kernels
#define F4PC  (HW4 / CHUNKS)   // 1536 f4 per chunk per channel
#define ITERS (F4PC / 256)     // 6
#define VALID_THR 1e-6f
#define MAXD 20.0f
#define NPART 2048             // 16*128
#define NSTAT 23               // 0:n 1:y 2:y2 3+c:x 7+c:x2 11+c:xy 15+c:xmin 19+c:xmax

__device__ inline double wred_sum(double v) {
#pragma unroll
    for (int o = 32; o > 0; o >>= 1) v += __shfl_down(v, o, 64);
    return v;
}
__device__ inline double wred_min(double v) {
#pragma unroll
    for (int o = 32; o > 0; o >>= 1) v = fmin(v, __shfl_down(v, o, 64));
    return v;
}
__device__ inline double wred_max(double v) {
#pragma unroll
    for (int o = 32; o > 0; o >>= 1) v = fmax(v, __shfl_down(v, o, 64));
    return v;
}

// ---------------- pass 1: masked stats ----------------
__global__ __launch_bounds__(256) void k_reduce(const f4* __restrict__ nsd,
                                                const f4* __restrict__ sp,
                                                double* __restrict__ part) {
    const int blk = blockIdx.x;
    const int b = blk >> 7;
    const int chunk = blk & (CHUNKS - 1);
    const int t = threadIdx.x;
    const int sbase = b * HW4 + chunk * F4PC;

    float lnv = 0.f, lyv = 0.f, ly2 = 0.f;
    float lx[4] = {0, 0, 0, 0}, lx2[4] = {0, 0, 0, 0}, lxy[4] = {0, 0, 0, 0};
    float lmn[4] = {INFINITY, INFINITY, INFINITY, INFINITY};
    float lmx[4] = {-INFINITY, -INFINITY, -INFINITY, -INFINITY};
#pragma unroll
    for (int i = 0; i < ITERS; i++) {
        const int o = i * 256 + t;
        f4 s4 = sp[sbase + o];
        float mv[4], svm[4];
#pragma unroll
        for (int l = 0; l < 4; l++) {
            float sv = s4[l];
            mv[l] = (sv > VALID_THR && sv <= MAXD) ? 1.0f : 0.0f;
            svm[l] = sv * mv[l];
            lnv += mv[l];
            lyv += svm[l];
            ly2 = fmaf(sv * sv, mv[l], ly2);
        }
#pragma unroll
        for (int c = 0; c < 4; c++) {
            f4 x4 = nsd[(b * 4 + c) * HW4 + chunk * F4PC + o];
#pragma unroll
            for (int l = 0; l < 4; l++) {
                float xv = x4[l];
                lx[c]  = fmaf(xv, mv[l], lx[c]);
                lx2[c] = fmaf(xv * xv, mv[l], lx2[c]);
                lxy[c] = fmaf(xv, svm[l], lxy[c]);
                lmn[c] = fminf(lmn[c], mv[l] != 0.f ? xv : INFINITY);
                lmx[c] = fmaxf(lmx[c], mv[l] != 0.f ? xv : -INFINITY);
            }
        }
    }

    double vals[NSTAT] = {(double)lnv, (double)lyv, (double)ly2,
                          (double)lx[0],  (double)lx[1],  (double)lx[2],  (double)lx[3],
                          (double)lx2[0], (double)lx2[1], (double)lx2[2], (double)lx2[3],
                          (double)lxy[0], (double)lxy[1], (double)lxy[2], (double)lxy[3],
                          (double)lmn[0], (double)lmn[1], (double)lmn[2], (double)lmn[3],
                          (double)lmx[0], (double)lmx[1], (double)lmx[2], (double)lmx[3]};
    __shared__ double red[4][NSTAT];
    const int wv = t >> 6, lane = t & 63;
#pragma unroll
    for (int j = 0; j < NSTAT; j++) {
        double r = (j < 15) ? wred_sum(vals[j])
                 : (j < 19) ? wred_min(vals[j])
                            : wred_max(vals[j]);
        if (lane == 0) red[wv][j] = r;
    }
    __syncthreads();
    if (t < NSTAT) {
        double a0 = red[0][t], a1 = red[1][t], a2 = red[2][t], a3 = red[3][t];
        double r = (t < 15) ? (a0 + a1 + a2 + a3)
                 : (t < 19) ? fmin(fmin(a0, a1), fmin(a2, a3))
                            : fmax(fmax(a0, a1), fmax(a2, a3));
        part[t * NPART + blk] = r;
    }
}

// ---------------- solve + analytic mse + argmin ----------------
__global__ void k_solve(const double* __restrict__ part, float* __restrict__ wsf,
                        double* __restrict__ wsn, int* __restrict__ bidx,
                        int* __restrict__ flags, double* __restrict__ esum,
                        float* __restrict__ out_idx) {
    const int t = threadIdx.x;          // 768 threads; 736 active in stage 1
    __shared__ double sred[NSTAT][16];
    __shared__ double smse[64];
    __shared__ int snoclip[64];

    if (t < NSTAT * 32) {               // pair-split: 2 threads per (j,b) task
        const int j = t >> 5;           // stat
        const int rem = t & 31;
        const int b = rem >> 1;         // batch
        const int p = rem & 1;          // half
        const double* src = part + j * NPART + b * CHUNKS + p * 64;
        double acc;
        if (j < 15) {
            acc = 0.0;
#pragma unroll 8
            for (int k = 0; k < 64; k++) acc += src[k];
            acc += __shfl_down(acc, 1, 64);
        } else if (j < 19) {
            acc = INFINITY;
#pragma unroll 8
            for (int k = 0; k < 64; k++) acc = fmin(acc, src[k]);
            acc = fmin(acc, __shfl_down(acc, 1, 64));
        } else {
            acc = -INFINITY;
#pragma unroll 8
            for (int k = 0; k < 64; k++) acc = fmax(acc, src[k]);
            acc = fmax(acc, __shfl_down(acc, 1, 64));
        }
        if (p == 0) sred[j][b] = acc;
    }
    __syncthreads();

    if (t < 64) {
        const int b = t >> 2, c = t & 3;
        double n   = sred[0][b];
        double y   = sred[1][b];
        double y2  = sred[2][b];
        double x   = sred[3 + c][b];
        double x2  = sred[7 + c][b];
        double xy  = sred[11 + c][b];
        double xmn = sred[15 + c][b];
        double xmx = sred[19 + c][b];
        double det = n * x2 - x * x;
        bool ok = (n >= 10.0) && (fabs(det) >= 1e-8);
        double sdet = ok ? det : 1.0;
        double ad = ok ? (n * xy - x * y) / sdet : 1.0;
        double bd = ok ? (x2 * y - x * xy) / sdet : 0.0;
        float af = (float)ad, bf = (float)bd;
        wsf[t] = af;
        wsf[64 + t] = bf;
        if (c == 0) wsn[b] = n;
        esum[t] = 0.0;

        double mse;
        int noclip;
        if (n <= 0.0) {
            mse = INFINITY;
            noclip = 1;
        } else {
            double A = (double)af, B = (double)bf;
            double e0 = A * xmn + B, e1 = A * xmx + B;
            double clo = fmin(e0, e1), chi = fmax(e0, e1);
            noclip = (clo >= 0.0 && chi <= (double)MAXD) ? 1 : 0;
            mse = (A * A * x2 + 2.0 * A * B * x + B * B * n
                   - 2.0 * A * xy - 2.0 * B * y + y2) / fmax(n, 1.0);
        }
        smse[t] = mse;
        snoclip[t] = noclip;
    }
    __syncthreads();

    if (t < 16) {
        int fast = snoclip[t * 4] & snoclip[t * 4 + 1] & snoclip[t * 4 + 2] & snoclip[t * 4 + 3];
        flags[t] = fast ? 0 : 1;
        if (fast) {
            double best = INFINITY;
            int bc = 0;
            for (int cc = 0; cc < 4; cc++) {
                double m = smse[t * 4 + cc];
                if (m < best) { best = m; bc = cc; }
            }
            bidx[t] = bc;
            out_idx[t] = (float)bc;
        }
    }
}

// ---------------- pass 2: apply (+ exact err only if clipping detected) ----------------
__global__ __launch_bounds__(256) void k_apply(const f4* __restrict__ nsd,
                                               const f4* __restrict__ sp,
                                               const float* __restrict__ wsf,
                                               const int* __restrict__ bidx,
                                               const int* __restrict__ flags,
                                               double* __restrict__ esum,
                                               f4* __restrict__ out_corr,
                                               f4* __restrict__ out_best) {
    const int blk = blockIdx.x;
    const int b = blk >> 7;
    const int chunk = blk & (CHUNKS - 1);
    const int t = threadIdx.x;
    float sc[4], bi[4];
#pragma unroll
    for (int c = 0; c < 4; c++) {
        sc[c] = wsf[b * 4 + c];
        bi[c] = wsf[64 + b * 4 + c];
    }
    const int sbase = b * HW4 + chunk * F4PC;

    if (flags[b] == 0) {
        // fast path: no sp read, no err reduction; inline best-channel write.
        // REGULAR loads: hit L3-resident input, keep it MRU for next replay.
        const int cbest = bidx[b];
#pragma unroll
        for (int i = 0; i < ITERS; i++) {
            const int o = i * 256 + t;
#pragma unroll
            for (int c = 0; c < 4; c++) {
                const int off = (b * 4 + c) * HW4 + chunk * F4PC + o;
                f4 x4 = nsd[off];
                f4 o4;
#pragma unroll
                for (int l = 0; l < 4; l++)
                    o4[l] = fminf(fmaxf(fmaf(sc[c], x4[l], bi[c]), 0.0f), MAXD);
                __builtin_nontemporal_store(o4, &out_corr[off]);
                if (c == cbest)
                    __builtin_nontemporal_store(o4, &out_best[sbase + o]);
            }
        }
        return;
    }

    // slow path (a masked pixel would clip): exact per-pixel err
    float lerr[4] = {0, 0, 0, 0};
#pragma unroll
    for (int i = 0; i < ITERS; i++) {
        const int o = i * 256 + t;
        f4 s4 = sp[sbase + o];
        float mv[4];
#pragma unroll
        for (int l = 0; l < 4; l++)
            mv[l] = (s4[l] > VALID_THR && s4[l] <= MAXD) ? 1.0f : 0.0f;
#pragma unroll
        for (int c = 0; c < 4; c++) {
            const int off = (b * 4 + c) * HW4 + chunk * F4PC + o;
            f4 x4 = nsd[off];
            f4 o4;
#pragma unroll
            for (int l = 0; l < 4; l++)
                o4[l] = fminf(fmaxf(fmaf(sc[c], x4[l], bi[c]), 0.0f), MAXD);
            __builtin_nontemporal_store(o4, &out_corr[off]);
#pragma unroll
            for (int l = 0; l < 4; l++) {
                float d = o4[l] - s4[l];
                lerr[c] = fmaf(d * d, mv[l], lerr[c]);
            }
        }
    }
    __shared__ double red[4][4];
    const int wv = t >> 6, lane = t & 63;
#pragma unroll
    for (int j = 0; j < 4; j++) {
        double r = wred_sum((double)lerr[j]);
        if (lane == 0) red[wv][j] = r;
    }
    __syncthreads();
    if (t < 4)
        atomicAdd(&esum[b * 4 + t], red[0][t] + red[1][t] + red[2][t] + red[3][t]);
}

// ---------------- slow-path best copy ----------------
__global__ __launch_bounds__(256) void k_best(const f4* __restrict__ corr,
                                              const int* __restrict__ flags,
                                              const double* __restrict__ esum,
                                              const double* __restrict__ wsn,
                                              f4* __restrict__ out_best,
                                              float* __restrict__ out_idx) {
    const int b = blockIdx.x / 192;
    if (flags[b] == 0) return;          // out_best already written by k_apply
    const int i = blockIdx.x % 192;
    double n = wsn[b];
    double nm = fmax(n, 1.0);
    double best = INFINITY;
    int bc = 0;
    for (int cc = 0; cc < 4; cc++) {
        double mse = (n > 0.0) ? (esum[b * 4 + cc] / nm) : INFINITY;
        if (mse < best) { best = mse; bc = cc; }
    }
    if (i == 0 && threadIdx.x == 0) out_idx[b] = (float)bc;
    const int base = (b * 4 + bc) * HW4 + i * 1024 + threadIdx.x;
    const int obase = b * HW4 + i * 1024 + threadIdx.x;
#pragma unroll
    for (int k = 0; k < 4; k++) {
        f4 v = corr[base + k * 256];
        __builtin_nontemporal_store(v, &out_best[obase + k * 256]);
    }
}

extern "C" void kernel_launch(void* const* d_in, const int* in_sizes, int n_in,
                              void* d_out, int out_size, void* d_ws, size_t ws_size,
                              hipStream_t stream) {
    const f4* nsd = (const f4*)d_in[0];
    const f4* sp  = (const f4*)d_in[1];
    float* out = (float*)d_out;

    float* out_corr = out;                 // 16*4*768*1024
    float* out_best = out + 50331648;      // 16*1*768*1024
    float* out_idx  = out + 62914560;      // 16

    // pass-1 partials live in the out_best region (consumed by k_solve before
    // k_apply/k_best write real data there)
    double* part = (double*)out_best;      // 23*2048 doubles = 368 KB

    // tiny cross-kernel state in d_ws (~1.3 KB)
    float*  wsf   = (float*)d_ws;                    // scale[64], bias[64]
    double* wsn   = (double*)((char*)d_ws + 512);    // n[16]
    int*    bidx  = (int*)((char*)d_ws + 640);       // best idx[16]
    int*    flags = (int*)((char*)d_ws + 704);       // slow-path flags[16]
    double* esum  = (double*)((char*)d_ws + 768);    // exact err sums[64]

    k_reduce<<<NPART, 256, 0, stream>>>(nsd, sp, part);
    k_solve<<<1, 768, 0, stream>>>(part, wsf, wsn, bidx, flags, esum, out_idx);
    k_apply<<<NPART, 256, 0, stream>>>(nsd, sp, wsf, bidx, flags, esum,
                                       (f4*)out_corr, (f4*)out_best);
    k_best<<<3072, 256, 0, stream>>>((const f4*)out_corr, flags, esum, wsn,
                                     (f4*)out_best, out_idx);
}